// Round 9
// baseline (338.129 us; speedup 1.0000x reference)
//
#include <hip/hip_runtime.h>
#include <cstdint>
#include <cstddef>

// ---------- types ----------
typedef __bf16 bf16x8 __attribute__((ext_vector_type(8)));
typedef __bf16 bf16x4 __attribute__((ext_vector_type(4)));
typedef float  f32x4  __attribute__((ext_vector_type(4)));
typedef float  f32x16 __attribute__((ext_vector_type(16)));

// async global->LDS, 16B per lane, dest = wave-uniform base + lane*16
__device__ __forceinline__ void gload_lds16(const void* g, void* l) {
    __builtin_amdgcn_global_load_lds(
        (const __attribute__((address_space(1))) void*)g,
        (__attribute__((address_space(3))) void*)l, 16, 0, 0);
}

// counted-vmcnt "wait + barrier" fences. lgkmcnt(0) retires this wave's
// ds_reads so ring-buffer WAR reuse is protected by the barrier that follows.
#define VM6B asm volatile("s_waitcnt vmcnt(6) lgkmcnt(0)\ns_barrier" ::: "memory")
#define VM4B asm volatile("s_waitcnt vmcnt(4) lgkmcnt(0)\ns_barrier" ::: "memory")
#define VM0B asm volatile("s_waitcnt vmcnt(0) lgkmcnt(0)\ns_barrier" ::: "memory")
#define BARO asm volatile("s_barrier" ::: "memory")
#define WAITB4 asm volatile("s_waitcnt vmcnt(4) lgkmcnt(0)\ns_barrier" ::: "memory")
#define WAITB0 asm volatile("s_waitcnt vmcnt(0) lgkmcnt(0)\ns_barrier" ::: "memory")

// ---------- problem constants ----------
// B=2, S=2048, Hdim=2048, NH=16, KV=4, D=128
#define SEQ 2048
#define NH 16
#define NKV 4
#define HD 128

// ---------- fused f32 -> bf16 convert of all 5 inputs (one launch) ----------
__global__ __launch_bounds__(256) void cvt_all(const float* __restrict__ hs,
                                               const float* __restrict__ wq,
                                               const float* __restrict__ wk,
                                               const float* __restrict__ wv,
                                               const float* __restrict__ wo,
                                               __bf16* __restrict__ hB,
                                               __bf16* __restrict__ WqkB,
                                               __bf16* __restrict__ WvB,
                                               __bf16* __restrict__ WoB) {
    int bid = blockIdx.x;
    const float* in; __bf16* out; int base;
    if (bid < 8192)        { in = hs; out = hB;                   base = bid; }
    else if (bid < 12288)  { in = wq; out = WqkB;                 base = bid - 8192; }
    else if (bid < 13312)  { in = wk; out = WqkB + 2048 * 2048;   base = bid - 12288; }
    else if (bid < 14336)  { in = wv; out = WvB;                  base = bid - 13312; }
    else                   { in = wo; out = WoB;                  base = bid - 14336; }
    int i = base * 256 + threadIdx.x;
    float4 v = ((const float4*)in)[i];
    bf16x4 o = { (__bf16)v.x, (__bf16)v.y, (__bf16)v.z, (__bf16)v.w };
    ((bf16x4*)out)[i] = o;
}

// ============ 256x256 / BK=64 / 4-phase-per-tile / counted-vmcnt GEMM ============
__device__ __forceinline__ void stage_half(const __bf16* __restrict__ M,
                                           char* dbuf, int bmn, int k0, int half,
                                           int wave, int lane) {
    char* hb = dbuf + (half & 1) * 32768 + (half >> 1) * 16384;
    int kbase = k0 + (half >> 1) * 32;
#pragma unroll
    for (int g = 0; g < 2; ++g) {
        int c = wave * 2 + g;                 // chunk 0..15
        int row = (c & 3) * 64 + lane;        // row in 256-tile
        int ks = c >> 2;                      // slab within half
        gload_lds16(M + (size_t)(bmn + row) * 2048 + kbase + ks * 8, hb + c * 1024);
    }
}

template <int KS, int MH>
__device__ __forceinline__ void phase_mfma(const __bf16* bA, const __bf16* bB,
                                           int quad, int l16, int wr128, int colbase,
                                           bf16x8 (&bq)[4], f32x4 acc[8][4]) {
    bf16x8 af[4];
#pragma unroll
    for (int ii = 0; ii < 4; ++ii)
        af[ii] = *(const bf16x8*)(bA + (KS * 4 + quad) * 2048 +
                                  (wr128 + (MH * 4 + ii) * 16 + l16) * 8);
    if (MH == 0) {
#pragma unroll
        for (int j = 0; j < 4; ++j)
            bq[j] = *(const bf16x8*)(bB + (KS * 4 + quad) * 2048 +
                                     (colbase + (j & 1) * 16 + (j >> 1) * 64 + l16) * 8);
    }
    __builtin_amdgcn_s_setprio(1);
#pragma unroll
    for (int ii = 0; ii < 4; ++ii)
#pragma unroll
        for (int j = 0; j < 4; ++j)
            acc[MH * 4 + ii][j] = __builtin_amdgcn_mfma_f32_16x16x32_bf16(
                af[ii], bq[j], acc[MH * 4 + ii][j], 0, 0, 0);
    __builtin_amdgcn_s_setprio(0);
}

__device__ __forceinline__ void gemm_core(const __bf16* __restrict__ A,
                                          const __bf16* __restrict__ B,
                                          char* lds, int bm, int bn,
                                          int wave, int lane, int quad, int l16,
                                          int wr128, int colbase, f32x4 acc[8][4]) {
    const int NT = 32;  // K = 2048
    stage_half(A, lds, bm, 0, 0, wave, lane);
    stage_half(B, lds, bn, 0, 1, wave, lane);
    stage_half(A, lds, bm, 0, 2, wave, lane);
    stage_half(B, lds, bn, 0, 3, wave, lane);
    int cur = 0;
    for (int t = 0; t < NT - 1; ++t) {
        const __bf16* bA = (const __bf16*)(lds + cur * 65536);
        const __bf16* bB = (const __bf16*)(lds + cur * 65536 + 32768);
        char* nb = lds + (cur ^ 1) * 65536;
        int k1 = (t + 1) * 64;
        bf16x8 bq[4];
        stage_half(A, nb, bm, k1, 0, wave, lane);   // phase 0
        VM6B;
        phase_mfma<0, 0>(bA, bB, quad, l16, wr128, colbase, bq, acc);
        stage_half(B, nb, bn, k1, 1, wave, lane);   // phase 1
        BARO;
        phase_mfma<0, 1>(bA, bB, quad, l16, wr128, colbase, bq, acc);
        stage_half(A, nb, bm, k1, 2, wave, lane);   // phase 2
        VM6B;
        phase_mfma<1, 0>(bA, bB, quad, l16, wr128, colbase, bq, acc);
        stage_half(B, nb, bn, k1, 3, wave, lane);   // phase 3
        BARO;
        phase_mfma<1, 1>(bA, bB, quad, l16, wr128, colbase, bq, acc);
        cur ^= 1;
    }
    {
        const __bf16* bA = (const __bf16*)(lds + cur * 65536);
        const __bf16* bB = (const __bf16*)(lds + cur * 65536 + 32768);
        bf16x8 bq[4];
        VM4B;
        phase_mfma<0, 0>(bA, bB, quad, l16, wr128, colbase, bq, acc);
        phase_mfma<0, 1>(bA, bB, quad, l16, wr128, colbase, bq, acc);
        VM0B;
        phase_mfma<1, 0>(bA, bB, quad, l16, wr128, colbase, bq, acc);
        phase_mfma<1, 1>(bA, bB, quad, l16, wr128, colbase, bq, acc);
    }
}

// ---------- fused QKV projection GEMM, 256^2 tile, grid (16, 12) ----------
// y in [0,8):   C = hB @ Wq^T (heads 2y,2y+1) -> RoPE(+scale) -> Qr [B,NH,S,D]
// y in {8,9}:   C = hB @ Wk^T                 -> RoPE         -> Kr [B,KV,S,D]
// y in {10,11}: C = Wv_rows @ hB^T            -> plain        -> VT [KV*D][B*S]
__global__ __launch_bounds__(512, 2) void qkv_gemm(const __bf16* __restrict__ hB,
                                                   const __bf16* __restrict__ Wqk,
                                                   const __bf16* __restrict__ Wv,
                                                   __bf16* __restrict__ Qr,
                                                   __bf16* __restrict__ Kr,
                                                   __bf16* __restrict__ VT) {
    __shared__ __align__(16) char lds[2 * 65536];   // 128 KB double buffer
    const int tid = threadIdx.x;
    const int wave = tid >> 6, lane = tid & 63;
    const int quad = lane >> 4, l16 = lane & 15;
    const int wr = wave >> 2, wc = wave & 3;
    // XCD-aware bijective swizzle (nwg = 192, 192/8 = 24)
    int wg = blockIdx.y * 16 + blockIdx.x;
    wg = (wg & 7) * 24 + (wg >> 3);
    const int x = wg & 15, y = wg >> 4;
    const bool isVT = (y >= 10);
    const bool isQ = (y < 8);

    const __bf16* Amat = isVT ? Wv : hB;
    const __bf16* Bmat = isVT ? hB : (isQ ? Wqk : Wqk + 2048 * 2048);
    const int bm = isVT ? (y - 10) * 256 : x * 256;
    const int bn = isVT ? x * 256 : (isQ ? y * 256 : (y - 8) * 256);

    const int wr128 = wr * 128;
    const int colbase = (wc >> 1) * 128 + (wc & 1) * 32;

    f32x4 acc[8][4] = {};
    gemm_core(Amat, Bmat, lds, bm, bn, wave, lane, quad, l16, wr128, colbase, acc);

    if (isVT) {
#pragma unroll
        for (int i = 0; i < 8; ++i)
#pragma unroll
            for (int j = 0; j < 4; ++j) {
                int row = bm + wr128 + i * 16 + quad * 4;
                int col = bn + colbase + (j & 1) * 16 + (j >> 1) * 64 + l16;
#pragma unroll
                for (int r = 0; r < 4; ++r)
                    VT[(size_t)(row + r) * 4096 + col] = (__bf16)acc[i][j][r];
            }
    } else {
        __bf16* outp = isQ ? Qr : Kr;
        // Q scale = log2(e)/sqrt(128): folds softmax exp->exp2 into the
        // projection so attn can use raw v_exp_f32 (2^x). K scale = 1.
        const float sc = isQ ? 0.1275255128608411f : 1.0f;
        const int nh = isQ ? NH : NKV;
        const int hh = (isQ ? y * 2 : (y - 8) * 2) + (wc >> 1);
#pragma unroll
        for (int j2 = 0; j2 < 2; ++j2) {
            int d = (wc & 1) * 32 + j2 * 16 + l16;              // 0..63
            float inv = exp2f(-(float)d * 0.2076205059304601f); // log2(1e4)/64
#pragma unroll
            for (int i = 0; i < 8; ++i)
#pragma unroll
                for (int r = 0; r < 4; ++r) {
                    int m = bm + wr128 + i * 16 + quad * 4 + r;
                    int s = m & (SEQ - 1), b = m >> 11;
                    float f = (float)s * inv;
                    float c = __cosf(f) * sc, sn = __sinf(f) * sc;
                    float x1 = acc[i][j2][r], x2 = acc[i][j2 + 2][r];
                    size_t rb = ((size_t)(b * nh + hh) * SEQ + s) * HD;
                    outp[rb + d]      = (__bf16)(x1 * c - x2 * sn);
                    outp[rb + d + 64] = (__bf16)(x2 * c + x1 * sn);
                }
        }
    }
}

// ---------- B^T GEMM (Wo projection), 128x256 tile, grid 256 blocks ----------
__global__ __launch_bounds__(512, 1) void gemm_bt_f32(const __bf16* __restrict__ A,
                                                      const __bf16* __restrict__ W,
                                                      float* __restrict__ C) {
    __shared__ __align__(16) char lds[3 * 49152];   // 144 KB ring
    const int tid = threadIdx.x;
    const int wave = tid >> 6, lane = tid & 63;
    const int quad = lane >> 4, l16 = lane & 15;
    const int wr = wave >> 2, wc = wave & 3;        // wave tile 64x64
    // XCD swizzle (nwg = 256, 256/8 = 32)
    int wg = blockIdx.y * 32 + blockIdx.x;
    wg = (wg & 7) * 32 + (wg >> 3);
    const int bm = (wg & 31) * 128, bn = (wg >> 5) * 256;

    f32x4 acc[4][4] = {};

    auto stageT = [&](int sb, int k0) {
        char* dst = lds + sb * 49152;
#pragma unroll
        for (int tt = 0; tt < 6; ++tt) {
            int c = wave * 6 + tt;              // 0..47
            if (c < 16) {
                int row = ((c & 1) << 6) + lane;
                gload_lds16(A + (size_t)(bm + row) * 2048 + k0 + (c >> 1) * 8,
                            dst + c * 1024);
            } else {
                int vc = c - 16;
                int row = ((vc & 3) << 6) + lane;
                gload_lds16(W + (size_t)(bn + row) * 2048 + k0 + (vc >> 2) * 8,
                            dst + 16384 + vc * 1024);
            }
        }
    };

    auto computeT = [&](int cb2) {
        const __bf16* bA = (const __bf16*)(lds + cb2 * 49152);  // [8][128][8]
        const __bf16* bB = bA + 8192;                            // [8][256][8]
#pragma unroll
        for (int ks = 0; ks < 2; ++ks) {
            bf16x8 af[4], bq[4];
#pragma unroll
            for (int i = 0; i < 4; ++i)
                af[i] = *(const bf16x8*)(bA + (ks * 4 + quad) * 1024 +
                                         (wr * 64 + i * 16 + l16) * 8);
#pragma unroll
            for (int j = 0; j < 4; ++j)
                bq[j] = *(const bf16x8*)(bB + (ks * 4 + quad) * 2048 +
                                         (wc * 64 + j * 16 + l16) * 8);
            __builtin_amdgcn_s_setprio(1);
#pragma unroll
            for (int i = 0; i < 4; ++i)
#pragma unroll
                for (int j = 0; j < 4; ++j)
                    acc[i][j] = __builtin_amdgcn_mfma_f32_16x16x32_bf16(
                        af[i], bq[j], acc[i][j], 0, 0, 0);
            __builtin_amdgcn_s_setprio(0);
        }
    };

    stageT(0, 0);
    stageT(1, 64);
    int cb = 0;
    for (int t = 0; t < 31; ++t) {
        VM6B;
        if (t < 30) {
            int sb = cb + 2; if (sb >= 3) sb -= 3;
            stageT(sb, (t + 2) * 64);
        }
        computeT(cb);
        if (++cb == 3) cb = 0;
    }
    VM0B;
    computeT(cb);

#pragma unroll
    for (int i = 0; i < 4; ++i)
#pragma unroll
        for (int j = 0; j < 4; ++j) {
            int row = bm + wr * 64 + i * 16 + quad * 4;
            int col = bn + wc * 64 + j * 16 + l16;
#pragma unroll
            for (int r = 0; r < 4; ++r)
                C[(size_t)(row + r) * 2048 + col] = acc[i][j][r];
        }
}

// ---------- flash attention: 4 waves, q-tile 128, kpos-tile 32, ----------
// ---------- 3-ring counted vmcnt, 2 blocks/CU, 32x32x16 MFMA ----------
// Per tile per wave: 8 MFMA-32 for QK^T (one 32x32 S covers all 32 q) +
// 8 MFMA-32 for PV (4 d-frags x 2 k-steps) = 16 MFMA-32 (was 32 MFMA-16).
// Operand map (32x32x16): lane l holds A[row=l&31][k=(l>>5)*8+j],
// B[k=(l>>5)*8+j][col=l&31]; C/D: col=lane&31, row=(r&3)+8*(r>>2)+4*(l>>5)
// (m74/m101-verified). LDS traffic unchanged vs r8.
__global__ __launch_bounds__(256, 2) void attn_kernel(const __bf16* __restrict__ Q,
                                                      const __bf16* __restrict__ Kr,
                                                      const __bf16* __restrict__ VT,
                                                      __bf16* __restrict__ AO) {
    __shared__ __align__(16) char ring[3 * 16384];   // 48 KB: kt(8K)+vt(8K) x3
    __shared__ __align__(16) __bf16 Pb[4][32][40];   // 10 KB: [wave][q][kpos+pad]

    const int tid = threadIdx.x;
    const int wave = tid >> 6, lane = tid & 63;
    const int lo = lane & 31, hi = lane >> 5;
    // XCD swizzle over 512 blocks (512/8 = 64); x-fastest so blocks sharing
    // (h,b) [same K/V panel] land on the same XCD.
    int wg = (blockIdx.z * 16 + blockIdx.y) * 16 + blockIdx.x;
    wg = (wg & 7) * 64 + (wg >> 3);
    const int x = wg & 15, h = (wg >> 4) & 15, b = wg >> 8;
    const int kv = h >> 2;
    const int qbase = x * 128 + wave * 32;

    // Q B-fragments: lane l holds Q[q = qbase+lo][d = t*16 + hi*8 + 0..7]
    // (Q pre-scaled by log2e/sqrt(D) at projection time)
    bf16x8 qf[8];
    {
        const __bf16* Qp = Q + ((size_t)(b * NH + h) * SEQ + qbase + lo) * HD;
#pragma unroll
        for (int t = 0; t < 8; ++t) qf[t] = *(const bf16x8*)(Qp + t * 16 + hi * 8);
    }

    const __bf16* Kp = Kr + (size_t)(b * NKV + kv) * SEQ * HD;
    const __bf16* Vp = VT + (size_t)(kv * HD) * (2 * SEQ) + b * SEQ;

    f32x16 oacc[4] = {};      // O^T[d = df*32 + row][q = lo], 4 d-frags
    float lpart = 0.f;        // sum over this lane's kpos-half for q = qbase+lo

    auto stage = [&](int sb, int k0) {
        char* dst = ring + sb * 16384;
#pragma unroll
        for (int tt = 0; tt < 4; ++tt) {
            int c = wave * 4 + tt;              // chunk 0..15
            if (c < 8) {                        // kt: slabs 2c,2c+1
                gload_lds16(Kp + (size_t)(k0 + (lane & 31)) * HD +
                                (2 * c + (lane >> 5)) * 8,
                            dst + c * 1024);
            } else {                            // vt: kslab vc>>1, d-half vc&1
                int vc = c - 8;
                gload_lds16(Vp + (size_t)(((vc & 1) << 6) + lane) * (2 * SEQ) + k0 +
                                (vc >> 1) * 8,
                            dst + 8192 + vc * 1024);
            }
        }
    };

    auto compute = [&](int cb) {
        const __bf16* kt = (const __bf16*)(ring + cb * 16384);  // [16][32][8]
        const __bf16* vt = kt + 4096;                            // [4][128][8]
        // S[kpos][q] = K_tile . Q^T : 8 d-steps of 32x32x16
        f32x16 s = {};
#pragma unroll
        for (int t = 0; t < 8; ++t) {
            bf16x8 ka = *(const bf16x8*)(kt + ((2 * t + hi) * 32 + lo) * 8);
            s = __builtin_amdgcn_mfma_f32_32x32x16_bf16(ka, qf[t], s, 0, 0, 0);
        }
        // softmax numerator; lane's col q = lo fixed -> single lpart
#pragma unroll
        for (int g = 0; g < 4; ++g) {
            bf16x4 pk;
#pragma unroll
            for (int r = 0; r < 4; ++r) {
                float p = __builtin_amdgcn_exp2f(s[g * 4 + r]);
                lpart += p;
                pk[r] = (__bf16)p;
            }
            // S row (kpos) = (r&3) + 8*g + 4*hi  ->  Pb[q][kpos]
            *(bf16x4*)&Pb[wave][lo][g * 8 + hi * 4] = pk;
        }
        // O^T += V_tile . P : A=V[d][k], B=P[k][q]; 2 k-steps x 4 d-frags
#pragma unroll
        for (int st = 0; st < 2; ++st) {
            bf16x8 pbf = *(const bf16x8*)&Pb[wave][lo][st * 16 + hi * 8];
#pragma unroll
            for (int df = 0; df < 4; ++df) {
                bf16x8 va = *(const bf16x8*)(vt + ((2 * st + hi) * 128 +
                                                   df * 32 + lo) * 8);
                oacc[df] = __builtin_amdgcn_mfma_f32_32x32x16_bf16(
                    va, pbf, oacc[df], 0, 0, 0);
            }
        }
    };

    // 64 tiles of kpos-32; 3-ring: stage targets cb+2 (WAR-safe), WAITB4 counted
    stage(0, 0);
    stage(1, 32);
    int cb = 0;
    for (int t = 0; t < 63; ++t) {
        WAITB4;                                   // tile t landed; t+1 in flight
        if (t < 62) {
            int sb = cb + 2; if (sb >= 3) sb -= 3;
            stage(sb, (t + 2) * 32);
        }
        compute(cb);
        if (++cb == 3) cb = 0;
    }
    WAITB0;                                       // final tile: drain
    compute(cb);

    // epilogue: combine kpos-halves (lanes l and l+32 share q), normalize, store
    lpart += __shfl_xor(lpart, 32);
    float inv = 1.f / lpart;
    {
        int q = qbase + lo;
        __bf16* aop = AO + ((size_t)(b * SEQ + q)) * (NH * HD) + h * HD;
#pragma unroll
        for (int df = 0; df < 4; ++df)
#pragma unroll
            for (int g = 0; g < 4; ++g) {
                bf16x4 ov;
#pragma unroll
                for (int r = 0; r < 4; ++r)
                    ov[r] = (__bf16)(oacc[df][g * 4 + r] * inv);
                // d = df*32 + (r&3) + 8*g + 4*hi
                *(bf16x4*)(aop + df * 32 + g * 8 + hi * 4) = ov;
            }
    }
}

// ---------- launch ----------
extern "C" void kernel_launch(void* const* d_in, const int* in_sizes, int n_in,
                              void* d_out, int out_size, void* d_ws, size_t ws_size,
                              hipStream_t stream) {
    const float* hs = (const float*)d_in[0];
    const float* Wq = (const float*)d_in[1];
    const float* Wk = (const float*)d_in[2];
    const float* Wv = (const float*)d_in[3];
    const float* Wo = (const float*)d_in[4];
    float* out = (float*)d_out;
    char* ws = (char*)d_ws;

    // workspace layout (bytes):
    //   Qr   [0,      16.78M)  [B][NH][S][D]
    //   Kr   [16.78M, 20.97M)  [B][KV][S][D]
    //   VT   [20.97M, 25.17M)  [KV*D][B*S]
    //   WoB  [25.17M, 33.56M)  [2048][2048]
    //   hB   [33.56M, 50.33M)  (dead after qkv)  -> AO alias (16.8 MB)
    //   WqkB [50.33M, 60.82M)  (dead after qkv)
    //   WvB  [60.82M, 62.91M)  (dead after qkv)
    __bf16* Qr   = (__bf16*)(ws + 0);
    __bf16* Kr   = (__bf16*)(ws + 16777216);
    __bf16* VT   = (__bf16*)(ws + 20971520);
    __bf16* WoB  = (__bf16*)(ws + 25165824);
    __bf16* hB   = (__bf16*)(ws + 33554432);
    __bf16* WqkB = (__bf16*)(ws + 50331648);
    __bf16* WvB  = (__bf16*)(ws + 60817408);
    __bf16* AO   = (__bf16*)(ws + 33554432);  // alias hB (dead after qkv)

    // 1) one fused convert launch
    cvt_all<<<18432, 256, 0, stream>>>(hs, Wq, Wk, Wv, Wo, hB, WqkB, WvB, WoB);

    // 2) fused Q/K/V projection + RoPE + transposes (256^2, 4-phase, swizzled)
    qkv_gemm<<<dim3(16, 12), 512, 0, stream>>>(hB, WqkB, WvB, Qr, Kr, VT);

    // 3) attention: 4-wave blocks, 2 blocks/CU, 3-ring, 32x32x16 MFMA
    attn_kernel<<<dim3(16, 16, 2), 256, 0, stream>>>(Qr, Kr, VT, AO);

    // 4) output projection (128x256, 256 blocks = full machine, 3-ring)
    gemm_bt_f32<<<dim3(32, 8), 512, 0, stream>>>(AO, WoB, out);
}

// Round 10
// 332.727 us; speedup vs baseline: 1.0162x; 1.0162x over previous
//
#include <hip/hip_runtime.h>
#include <cstdint>
#include <cstddef>

// ---------- types ----------
typedef __bf16 bf16x8 __attribute__((ext_vector_type(8)));
typedef __bf16 bf16x4 __attribute__((ext_vector_type(4)));
typedef float  f32x4  __attribute__((ext_vector_type(4)));

// async global->LDS, 16B per lane, dest = wave-uniform base + lane*16
__device__ __forceinline__ void gload_lds16(const void* g, void* l) {
    __builtin_amdgcn_global_load_lds(
        (const __attribute__((address_space(1))) void*)g,
        (__attribute__((address_space(3))) void*)l, 16, 0, 0);
}

// counted-vmcnt "wait + barrier" fences. lgkmcnt(0) retires this wave's
// ds_reads so ring-buffer WAR reuse is protected by the barrier that follows.
#define VM6B asm volatile("s_waitcnt vmcnt(6) lgkmcnt(0)\ns_barrier" ::: "memory")
#define VM4B asm volatile("s_waitcnt vmcnt(4) lgkmcnt(0)\ns_barrier" ::: "memory")
#define VM0B asm volatile("s_waitcnt vmcnt(0) lgkmcnt(0)\ns_barrier" ::: "memory")
#define BARO asm volatile("s_barrier" ::: "memory")
#define WAITB4 asm volatile("s_waitcnt vmcnt(4) lgkmcnt(0)\ns_barrier" ::: "memory")
#define WAITB0 asm volatile("s_waitcnt vmcnt(0) lgkmcnt(0)\ns_barrier" ::: "memory")

// ---------- problem constants ----------
// B=2, S=2048, Hdim=2048, NH=16, KV=4, D=128
#define SEQ 2048
#define NH 16
#define NKV 4
#define HD 128

// ---------- fused f32 -> bf16 convert, grid-stride (2048 blocks) ----------
// 18.87M floats total; tiny-block version (18432 x 4KB) paid launch/schedule
// churn. Grid-stride at 2048 blocks = 8/CU streams at HBM rate (G11).
__global__ __launch_bounds__(256) void cvt_all(const float* __restrict__ hs,
                                               const float* __restrict__ wq,
                                               const float* __restrict__ wk,
                                               const float* __restrict__ wv,
                                               const float* __restrict__ wo,
                                               __bf16* __restrict__ hB,
                                               __bf16* __restrict__ WqkB,
                                               __bf16* __restrict__ WvB,
                                               __bf16* __restrict__ WoB) {
    for (int bid = blockIdx.x; bid < 18432; bid += gridDim.x) {
        const float* in; __bf16* out; int base;
        if (bid < 8192)        { in = hs; out = hB;                   base = bid; }
        else if (bid < 12288)  { in = wq; out = WqkB;                 base = bid - 8192; }
        else if (bid < 13312)  { in = wk; out = WqkB + 2048 * 2048;   base = bid - 12288; }
        else if (bid < 14336)  { in = wv; out = WvB;                  base = bid - 13312; }
        else                   { in = wo; out = WoB;                  base = bid - 14336; }
        int i = base * 256 + threadIdx.x;
        float4 v = ((const float4*)in)[i];
        bf16x4 o = { (__bf16)v.x, (__bf16)v.y, (__bf16)v.z, (__bf16)v.w };
        ((bf16x4*)out)[i] = o;
    }
}

// ============ 256x256 / BK=64 / 4-phase-per-tile / counted-vmcnt GEMM ============
__device__ __forceinline__ void stage_half(const __bf16* __restrict__ M,
                                           char* dbuf, int bmn, int k0, int half,
                                           int wave, int lane) {
    char* hb = dbuf + (half & 1) * 32768 + (half >> 1) * 16384;
    int kbase = k0 + (half >> 1) * 32;
#pragma unroll
    for (int g = 0; g < 2; ++g) {
        int c = wave * 2 + g;                 // chunk 0..15
        int row = (c & 3) * 64 + lane;        // row in 256-tile
        int ks = c >> 2;                      // slab within half
        gload_lds16(M + (size_t)(bmn + row) * 2048 + kbase + ks * 8, hb + c * 1024);
    }
}

template <int KS, int MH>
__device__ __forceinline__ void phase_mfma(const __bf16* bA, const __bf16* bB,
                                           int quad, int l16, int wr128, int colbase,
                                           bf16x8 (&bq)[4], f32x4 acc[8][4]) {
    bf16x8 af[4];
#pragma unroll
    for (int ii = 0; ii < 4; ++ii)
        af[ii] = *(const bf16x8*)(bA + (KS * 4 + quad) * 2048 +
                                  (wr128 + (MH * 4 + ii) * 16 + l16) * 8);
    if (MH == 0) {
#pragma unroll
        for (int j = 0; j < 4; ++j)
            bq[j] = *(const bf16x8*)(bB + (KS * 4 + quad) * 2048 +
                                     (colbase + (j & 1) * 16 + (j >> 1) * 64 + l16) * 8);
    }
    __builtin_amdgcn_s_setprio(1);
#pragma unroll
    for (int ii = 0; ii < 4; ++ii)
#pragma unroll
        for (int j = 0; j < 4; ++j)
            acc[MH * 4 + ii][j] = __builtin_amdgcn_mfma_f32_16x16x32_bf16(
                af[ii], bq[j], acc[MH * 4 + ii][j], 0, 0, 0);
    __builtin_amdgcn_s_setprio(0);
}

__device__ __forceinline__ void gemm_core(const __bf16* __restrict__ A,
                                          const __bf16* __restrict__ B,
                                          char* lds, int bm, int bn,
                                          int wave, int lane, int quad, int l16,
                                          int wr128, int colbase, f32x4 acc[8][4]) {
    const int NT = 32;  // K = 2048
    stage_half(A, lds, bm, 0, 0, wave, lane);
    stage_half(B, lds, bn, 0, 1, wave, lane);
    stage_half(A, lds, bm, 0, 2, wave, lane);
    stage_half(B, lds, bn, 0, 3, wave, lane);
    int cur = 0;
    for (int t = 0; t < NT - 1; ++t) {
        const __bf16* bA = (const __bf16*)(lds + cur * 65536);
        const __bf16* bB = (const __bf16*)(lds + cur * 65536 + 32768);
        char* nb = lds + (cur ^ 1) * 65536;
        int k1 = (t + 1) * 64;
        bf16x8 bq[4];
        stage_half(A, nb, bm, k1, 0, wave, lane);   // phase 0
        VM6B;
        phase_mfma<0, 0>(bA, bB, quad, l16, wr128, colbase, bq, acc);
        stage_half(B, nb, bn, k1, 1, wave, lane);   // phase 1
        BARO;
        phase_mfma<0, 1>(bA, bB, quad, l16, wr128, colbase, bq, acc);
        stage_half(A, nb, bm, k1, 2, wave, lane);   // phase 2
        VM6B;
        phase_mfma<1, 0>(bA, bB, quad, l16, wr128, colbase, bq, acc);
        stage_half(B, nb, bn, k1, 3, wave, lane);   // phase 3
        BARO;
        phase_mfma<1, 1>(bA, bB, quad, l16, wr128, colbase, bq, acc);
        cur ^= 1;
    }
    {
        const __bf16* bA = (const __bf16*)(lds + cur * 65536);
        const __bf16* bB = (const __bf16*)(lds + cur * 65536 + 32768);
        bf16x8 bq[4];
        VM4B;
        phase_mfma<0, 0>(bA, bB, quad, l16, wr128, colbase, bq, acc);
        phase_mfma<0, 1>(bA, bB, quad, l16, wr128, colbase, bq, acc);
        VM0B;
        phase_mfma<1, 0>(bA, bB, quad, l16, wr128, colbase, bq, acc);
        phase_mfma<1, 1>(bA, bB, quad, l16, wr128, colbase, bq, acc);
    }
}

// ---------- fused QKV projection GEMM, 256^2 tile, grid (16, 12) ----------
// y in [0,8):   C = hB @ Wq^T (heads 2y,2y+1) -> RoPE(+scale) -> Qr [B,NH,S,D]
// y in {8,9}:   C = hB @ Wk^T                 -> RoPE         -> Kr [B,KV,S,D]
// y in {10,11}: C = Wv_rows @ hB^T            -> plain        -> VT [KV*D][B*S]
__global__ __launch_bounds__(512, 2) void qkv_gemm(const __bf16* __restrict__ hB,
                                                   const __bf16* __restrict__ Wqk,
                                                   const __bf16* __restrict__ Wv,
                                                   __bf16* __restrict__ Qr,
                                                   __bf16* __restrict__ Kr,
                                                   __bf16* __restrict__ VT) {
    __shared__ __align__(16) char lds[2 * 65536];   // 128 KB double buffer
    const int tid = threadIdx.x;
    const int wave = tid >> 6, lane = tid & 63;
    const int quad = lane >> 4, l16 = lane & 15;
    const int wr = wave >> 2, wc = wave & 3;
    // XCD-aware bijective swizzle (nwg = 192, 192/8 = 24)
    int wg = blockIdx.y * 16 + blockIdx.x;
    wg = (wg & 7) * 24 + (wg >> 3);
    const int x = wg & 15, y = wg >> 4;
    const bool isVT = (y >= 10);
    const bool isQ = (y < 8);

    const __bf16* Amat = isVT ? Wv : hB;
    const __bf16* Bmat = isVT ? hB : (isQ ? Wqk : Wqk + 2048 * 2048);
    const int bm = isVT ? (y - 10) * 256 : x * 256;
    const int bn = isVT ? x * 256 : (isQ ? y * 256 : (y - 8) * 256);

    const int wr128 = wr * 128;
    const int colbase = (wc >> 1) * 128 + (wc & 1) * 32;

    f32x4 acc[8][4] = {};
    gemm_core(Amat, Bmat, lds, bm, bn, wave, lane, quad, l16, wr128, colbase, acc);

    if (isVT) {
#pragma unroll
        for (int i = 0; i < 8; ++i)
#pragma unroll
            for (int j = 0; j < 4; ++j) {
                int row = bm + wr128 + i * 16 + quad * 4;
                int col = bn + colbase + (j & 1) * 16 + (j >> 1) * 64 + l16;
#pragma unroll
                for (int r = 0; r < 4; ++r)
                    VT[(size_t)(row + r) * 4096 + col] = (__bf16)acc[i][j][r];
            }
    } else {
        __bf16* outp = isQ ? Qr : Kr;
        // Q scale = log2(e)/sqrt(128): folds softmax exp->exp2 into the
        // projection so attn can use raw v_exp_f32 (2^x). K scale = 1.
        const float sc = isQ ? 0.1275255128608411f : 1.0f;
        const int nh = isQ ? NH : NKV;
        const int hh = (isQ ? y * 2 : (y - 8) * 2) + (wc >> 1);
#pragma unroll
        for (int j2 = 0; j2 < 2; ++j2) {
            int d = (wc & 1) * 32 + j2 * 16 + l16;              // 0..63
            float inv = exp2f(-(float)d * 0.2076205059304601f); // log2(1e4)/64
#pragma unroll
            for (int i = 0; i < 8; ++i)
#pragma unroll
                for (int r = 0; r < 4; ++r) {
                    int m = bm + wr128 + i * 16 + quad * 4 + r;
                    int s = m & (SEQ - 1), b = m >> 11;
                    float f = (float)s * inv;
                    float c = __cosf(f) * sc, sn = __sinf(f) * sc;
                    float x1 = acc[i][j2][r], x2 = acc[i][j2 + 2][r];
                    size_t rb = ((size_t)(b * nh + hh) * SEQ + s) * HD;
                    outp[rb + d]      = (__bf16)(x1 * c - x2 * sn);
                    outp[rb + d + 64] = (__bf16)(x2 * c + x1 * sn);
                }
        }
    }
}

// ---------- B^T GEMM (Wo projection), 128x256 tile, grid 256 blocks ----------
__global__ __launch_bounds__(512, 1) void gemm_bt_f32(const __bf16* __restrict__ A,
                                                      const __bf16* __restrict__ W,
                                                      float* __restrict__ C) {
    __shared__ __align__(16) char lds[3 * 49152];   // 144 KB ring
    const int tid = threadIdx.x;
    const int wave = tid >> 6, lane = tid & 63;
    const int quad = lane >> 4, l16 = lane & 15;
    const int wr = wave >> 2, wc = wave & 3;        // wave tile 64x64
    // XCD swizzle (nwg = 256, 256/8 = 32)
    int wg = blockIdx.y * 32 + blockIdx.x;
    wg = (wg & 7) * 32 + (wg >> 3);
    const int bm = (wg & 31) * 128, bn = (wg >> 5) * 256;

    f32x4 acc[4][4] = {};

    auto stageT = [&](int sb, int k0) {
        char* dst = lds + sb * 49152;
#pragma unroll
        for (int tt = 0; tt < 6; ++tt) {
            int c = wave * 6 + tt;              // 0..47
            if (c < 16) {
                int row = ((c & 1) << 6) + lane;
                gload_lds16(A + (size_t)(bm + row) * 2048 + k0 + (c >> 1) * 8,
                            dst + c * 1024);
            } else {
                int vc = c - 16;
                int row = ((vc & 3) << 6) + lane;
                gload_lds16(W + (size_t)(bn + row) * 2048 + k0 + (vc >> 2) * 8,
                            dst + 16384 + vc * 1024);
            }
        }
    };

    auto computeT = [&](int cb2) {
        const __bf16* bA = (const __bf16*)(lds + cb2 * 49152);  // [8][128][8]
        const __bf16* bB = bA + 8192;                            // [8][256][8]
#pragma unroll
        for (int ks = 0; ks < 2; ++ks) {
            bf16x8 af[4], bq[4];
#pragma unroll
            for (int i = 0; i < 4; ++i)
                af[i] = *(const bf16x8*)(bA + (ks * 4 + quad) * 1024 +
                                         (wr * 64 + i * 16 + l16) * 8);
#pragma unroll
            for (int j = 0; j < 4; ++j)
                bq[j] = *(const bf16x8*)(bB + (ks * 4 + quad) * 2048 +
                                         (wc * 64 + j * 16 + l16) * 8);
            __builtin_amdgcn_s_setprio(1);
#pragma unroll
            for (int i = 0; i < 4; ++i)
#pragma unroll
                for (int j = 0; j < 4; ++j)
                    acc[i][j] = __builtin_amdgcn_mfma_f32_16x16x32_bf16(
                        af[i], bq[j], acc[i][j], 0, 0, 0);
            __builtin_amdgcn_s_setprio(0);
        }
    };

    stageT(0, 0);
    stageT(1, 64);
    int cb = 0;
    for (int t = 0; t < 31; ++t) {
        VM6B;
        if (t < 30) {
            int sb = cb + 2; if (sb >= 3) sb -= 3;
            stageT(sb, (t + 2) * 64);
        }
        computeT(cb);
        if (++cb == 3) cb = 0;
    }
    VM0B;
    computeT(cb);

#pragma unroll
    for (int i = 0; i < 4; ++i)
#pragma unroll
        for (int j = 0; j < 4; ++j) {
            int row = bm + wr * 64 + i * 16 + quad * 4;
            int col = bn + wc * 64 + j * 16 + l16;
#pragma unroll
            for (int r = 0; r < 4; ++r)
                C[(size_t)(row + r) * 2048 + col] = acc[i][j][r];
        }
}

// ---------- flash attention (r8 structure, best measured 91.4 us): ----------
// ---------- 4 waves, q-tile 128, kpos-tile 32, 3-ring counted vmcnt, ----------
// ---------- 2 blocks/CU, v_exp_f32 softmax ----------
__global__ __launch_bounds__(256, 2) void attn_kernel(const __bf16* __restrict__ Q,
                                                      const __bf16* __restrict__ Kr,
                                                      const __bf16* __restrict__ VT,
                                                      __bf16* __restrict__ AO) {
    __shared__ __align__(16) char ring[3 * 16384];   // 48 KB: kt(8K)+vt(8K) x3
    __shared__ __align__(16) __bf16 Pb[4][32][40];   // 10 KB: [wave][q][kpos+pad]

    const int tid = threadIdx.x;
    const int wave = tid >> 6, lane = tid & 63;
    const int quad = lane >> 4, l16 = lane & 15;
    // XCD swizzle over 512 blocks (512/8 = 64); x-fastest so blocks sharing
    // (h,b) [same K/V panel] land on the same XCD.
    int wg = (blockIdx.z * 16 + blockIdx.y) * 16 + blockIdx.x;
    wg = (wg & 7) * 64 + (wg >> 3);
    const int x = wg & 15, h = (wg >> 4) & 15, b = wg >> 8;
    const int kv = h >> 2;
    const int qbase = x * 128 + wave * 32;

    // Q fragments in registers (scaled by log2e/sqrt(D) at projection time)
    bf16x8 qf[2][4];
#pragma unroll
    for (int qs = 0; qs < 2; ++qs) {
        const __bf16* Qp =
            Q + ((size_t)(b * NH + h) * SEQ + qbase + qs * 16 + l16) * HD + quad * 8;
#pragma unroll
        for (int kq = 0; kq < 4; ++kq) qf[qs][kq] = *(const bf16x8*)(Qp + kq * 32);
    }

    const __bf16* Kp = Kr + (size_t)(b * NKV + kv) * SEQ * HD;
    const __bf16* Vp = VT + (size_t)(kv * HD) * (2 * SEQ) + b * SEQ;

    f32x4 oacc[2][8] = {};
    float lpart[2] = {0.f, 0.f};

    auto stage = [&](int sb, int k0) {
        char* dst = ring + sb * 16384;
#pragma unroll
        for (int tt = 0; tt < 4; ++tt) {
            int c = wave * 4 + tt;              // chunk 0..15
            if (c < 8) {                        // kt: slabs 2c,2c+1
                gload_lds16(Kp + (size_t)(k0 + (lane & 31)) * HD +
                                (2 * c + (lane >> 5)) * 8,
                            dst + c * 1024);
            } else {                            // vt: kslab vc>>1, d-half vc&1
                int vc = c - 8;
                gload_lds16(Vp + (size_t)(((vc & 1) << 6) + lane) * (2 * SEQ) + k0 +
                                (vc >> 1) * 8,
                            dst + 8192 + vc * 1024);
            }
        }
    };

    auto compute = [&](int cb) {
        const __bf16* kt = (const __bf16*)(ring + cb * 16384);  // [16][32][8]
        const __bf16* vt = kt + 4096;                            // [4][128][8]
        // S^T tile (32 q x 32 kpos per q-set): ka shared by both q-sets
#pragma unroll
        for (int mt = 0; mt < 2; ++mt) {
            f32x4 s0 = {0.f, 0.f, 0.f, 0.f}, s1 = {0.f, 0.f, 0.f, 0.f};
#pragma unroll
            for (int kq = 0; kq < 4; ++kq) {
                bf16x8 ka = *(const bf16x8*)(kt + (kq * 4 + quad) * 256 +
                                             (mt * 16 + l16) * 8);
                s0 = __builtin_amdgcn_mfma_f32_16x16x32_bf16(ka, qf[0][kq], s0, 0, 0, 0);
                s1 = __builtin_amdgcn_mfma_f32_16x16x32_bf16(ka, qf[1][kq], s1, 0, 0, 0);
            }
            bf16x4 pk0, pk1;
#pragma unroll
            for (int r = 0; r < 4; ++r) {
                // Q pre-scaled by log2e/sqrt(D): raw v_exp_f32 (2^x), single inst
                float p0 = __builtin_amdgcn_exp2f(s0[r]);
                float p1 = __builtin_amdgcn_exp2f(s1[r]);
                lpart[0] += p0; lpart[1] += p1;
                pk0[r] = (__bf16)p0; pk1[r] = (__bf16)p1;
            }
            *(bf16x4*)&Pb[wave][l16][mt * 16 + quad * 4] = pk0;
            *(bf16x4*)&Pb[wave][16 + l16][mt * 16 + quad * 4] = pk1;
        }
        // O^T += VT_tile @ P^T; va shared by both q-sets
        bf16x8 pb0 = *(const bf16x8*)&Pb[wave][l16][quad * 8];
        bf16x8 pb1 = *(const bf16x8*)&Pb[wave][16 + l16][quad * 8];
#pragma unroll
        for (int mt = 0; mt < 8; ++mt) {
            bf16x8 va = *(const bf16x8*)(vt + quad * 1024 + (mt * 16 + l16) * 8);
            oacc[0][mt] = __builtin_amdgcn_mfma_f32_16x16x32_bf16(
                va, pb0, oacc[0][mt], 0, 0, 0);
            oacc[1][mt] = __builtin_amdgcn_mfma_f32_16x16x32_bf16(
                va, pb1, oacc[1][mt], 0, 0, 0);
        }
    };

    // 64 tiles of kpos-32; 3-ring: stage targets cb+2 (WAR-safe), WAITB4 counted
    stage(0, 0);
    stage(1, 32);
    int cb = 0;
    for (int t = 0; t < 63; ++t) {
        WAITB4;                                   // tile t landed; t+1 in flight
        if (t < 62) {
            int sb = cb + 2; if (sb >= 3) sb -= 3;
            stage(sb, (t + 2) * 32);
        }
        compute(cb);
        if (++cb == 3) cb = 0;
    }
    WAITB0;                                       // final tile: drain
    compute(cb);

    // epilogue: normalize in-kernel, write bf16 AO
#pragma unroll
    for (int qs = 0; qs < 2; ++qs) {
        lpart[qs] += __shfl_xor(lpart[qs], 16);
        lpart[qs] += __shfl_xor(lpart[qs], 32);
        float inv = 1.f / lpart[qs];
        int q = qbase + qs * 16 + l16;
#pragma unroll
        for (int mt = 0; mt < 8; ++mt) {
            bf16x4 ov;
#pragma unroll
            for (int r = 0; r < 4; ++r) ov[r] = (__bf16)(oacc[qs][mt][r] * inv);
            *(bf16x4*)(AO + ((size_t)(b * SEQ + q)) * (NH * HD) + h * HD +
                       mt * 16 + quad * 4) = ov;
        }
    }
}

// ---------- launch ----------
extern "C" void kernel_launch(void* const* d_in, const int* in_sizes, int n_in,
                              void* d_out, int out_size, void* d_ws, size_t ws_size,
                              hipStream_t stream) {
    const float* hs = (const float*)d_in[0];
    const float* Wq = (const float*)d_in[1];
    const float* Wk = (const float*)d_in[2];
    const float* Wv = (const float*)d_in[3];
    const float* Wo = (const float*)d_in[4];
    float* out = (float*)d_out;
    char* ws = (char*)d_ws;

    // workspace layout (bytes):
    //   Qr   [0,      16.78M)  [B][NH][S][D]
    //   Kr   [16.78M, 20.97M)  [B][KV][S][D]
    //   VT   [20.97M, 25.17M)  [KV*D][B*S]
    //   WoB  [25.17M, 33.56M)  [2048][2048]
    //   hB   [33.56M, 50.33M)  (dead after qkv)  -> AO alias (16.8 MB)
    //   WqkB [50.33M, 60.82M)  (dead after qkv)
    //   WvB  [60.82M, 62.91M)  (dead after qkv)
    __bf16* Qr   = (__bf16*)(ws + 0);
    __bf16* Kr   = (__bf16*)(ws + 16777216);
    __bf16* VT   = (__bf16*)(ws + 20971520);
    __bf16* WoB  = (__bf16*)(ws + 25165824);
    __bf16* hB   = (__bf16*)(ws + 33554432);
    __bf16* WqkB = (__bf16*)(ws + 50331648);
    __bf16* WvB  = (__bf16*)(ws + 60817408);
    __bf16* AO   = (__bf16*)(ws + 33554432);  // alias hB (dead after qkv)

    // 1) one fused convert launch (grid-stride, 2048 blocks = 8/CU)
    cvt_all<<<2048, 256, 0, stream>>>(hs, Wq, Wk, Wv, Wo, hB, WqkB, WvB, WoB);

    // 2) fused Q/K/V projection + RoPE + transposes (256^2, 4-phase, swizzled)
    qkv_gemm<<<dim3(16, 12), 512, 0, stream>>>(hB, WqkB, WvB, Qr, Kr, VT);

    // 3) attention: 4-wave blocks, 2 blocks/CU, 3-ring counted vmcnt
    attn_kernel<<<dim3(16, 16, 2), 256, 0, stream>>>(Qr, Kr, VT, AO);

    // 4) output projection (128x256, 256 blocks = full machine, 3-ring)
    gemm_bt_f32<<<dim3(32, 8), 512, 0, stream>>>(AO, WoB, out);
}